// Round 14
// baseline (23.855 us; speedup 1.0000x reference)
//
#include <hip/hip_runtime.h>

#define Q 8                // index-stripes per person (sample partition; grid = n*Q blocks)
#define NR 8               // register-held verts per thread (2 groups x 4 verts)

// ---------------------------------------------------------------------------
// R26 = R25 (best, 23.7 us) with float2-vectorized bounds/hold loads: each
// thread loads two 4-vert groups as 6 x float2 each (12 VMEM issues vs 24
// scalar; float2 is always 8-B aligned since person stride V*3*4 = 82680 B
// is 8-B aligned; float4 would be misaligned for odd persons). Component
// mapping is compile-time. Identical float bits feed identical expressions:
// raster atomic set bit-identical (order-free atomicMin), c4 bit-identical
// (exact fmin/fmax), sample phase byte-identical -> absmax 0.0.
// ---------------------------------------------------------------------------
__global__ __launch_bounds__(1024) void k_fused(const float* __restrict__ verts,
                                                const float* __restrict__ trans,
                                                float* __restrict__ part,
                                                int V, int n,
                                                const int* __restrict__ pP) {
    __shared__ int   grid[32 * 1024];      // full 32^3 d^2 bits, 128 KB
    __shared__ float red[16][6];
    __shared__ float c4s[4];
    __shared__ float racc[16];

    int bq  = blockIdx.x;
    int p   = bq / Q;
    int q   = bq - p * Q;
    int tid = threadIdx.x, lane = tid & 63, wave = tid >> 6;

    // init full grid: 8192 int4 stores, 8 per thread, conflict-free
    {
        int4* g4 = (int4*)grid;
        int4  fill = make_int4(0x7F7F7F7F, 0x7F7F7F7F, 0x7F7F7F7F, 0x7F7F7F7F);
        #pragma unroll
        for (int k = 0; k < 8; ++k) g4[tid + (k << 10)] = fill;
    }

    const float* vp = verts + (size_t)p * V * 3;
    int G4 = V >> 2;                       // full 4-vert groups
    int GH = min(G4, 2048);                // groups held in registers (2/thread)
    const float2* v2 = (const float2*)vp;  // 8-B aligned for every person

    // --- 1. load own verts (float2 groups) + bounds ------------------------
    float rx[NR], ry[NR], rz[NR];
    {
        float mnx = 3.4e38f, mny = 3.4e38f, mnz = 3.4e38f;
        float mxx = -3.4e38f, mxy = -3.4e38f, mxz = -3.4e38f;
        #pragma unroll
        for (int gg = 0; gg < 2; ++gg) {
            int gi = tid + (gg << 10);
            int rb = gg << 2;
            if (gi < GH) {
                const float2* g2 = v2 + 6 * gi;
                float2 f0 = g2[0], f1 = g2[1], f2v = g2[2];
                float2 f3 = g2[3], f4v = g2[4], f5 = g2[5];
                // verts 4gi..4gi+3, compile-time component roles
                rx[rb + 0] = f0.x;  ry[rb + 0] = f0.y;  rz[rb + 0] = f1.x;
                rx[rb + 1] = f1.y;  ry[rb + 1] = f2v.x; rz[rb + 1] = f2v.y;
                rx[rb + 2] = f3.x;  ry[rb + 2] = f3.y;  rz[rb + 2] = f4v.x;
                rx[rb + 3] = f4v.y; ry[rb + 3] = f5.x;  rz[rb + 3] = f5.y;
                #pragma unroll
                for (int r4 = 0; r4 < 4; ++r4) {
                    mnx = fminf(mnx, rx[rb + r4]); mxx = fmaxf(mxx, rx[rb + r4]);
                    mny = fminf(mny, ry[rb + r4]); mxy = fmaxf(mxy, ry[rb + r4]);
                    mnz = fminf(mnz, rz[rb + r4]); mxz = fmaxf(mxz, rz[rb + r4]);
                }
            } else {
                #pragma unroll
                for (int r4 = 0; r4 < 4; ++r4) {
                    rx[rb + r4] = 0.0f; ry[rb + r4] = 0.0f; rz[rb + r4] = 0.0f;
                }
            }
        }
        // scalar tail: verts beyond full held groups (V%4, or V > 8192 case)
        for (int j = (GH << 2) + tid; j < V; j += 1024) {
            float x = vp[3 * j + 0], y = vp[3 * j + 1], z = vp[3 * j + 2];
            mnx = fminf(mnx, x); mxx = fmaxf(mxx, x);
            mny = fminf(mny, y); mxy = fmaxf(mxy, y);
            mnz = fminf(mnz, z); mxz = fmaxf(mxz, z);
        }
        for (int m = 32; m > 0; m >>= 1) {
            mnx = fminf(mnx, __shfl_xor(mnx, m)); mxx = fmaxf(mxx, __shfl_xor(mxx, m));
            mny = fminf(mny, __shfl_xor(mny, m)); mxy = fmaxf(mxy, __shfl_xor(mxy, m));
            mnz = fminf(mnz, __shfl_xor(mnz, m)); mxz = fmaxf(mxz, __shfl_xor(mxz, m));
        }
        if (lane == 0) {
            red[wave][0] = mnx; red[wave][1] = mny; red[wave][2] = mnz;
            red[wave][3] = mxx; red[wave][4] = mxy; red[wave][5] = mxz;
        }
        __syncthreads();
        if (tid == 0) {
            float a0 = red[0][0], a1 = red[0][1], a2 = red[0][2];
            float b0 = red[0][3], b1 = red[0][4], b2 = red[0][5];
            for (int w = 1; w < 16; ++w) {
                a0 = fminf(a0, red[w][0]); a1 = fminf(a1, red[w][1]); a2 = fminf(a2, red[w][2]);
                b0 = fmaxf(b0, red[w][3]); b1 = fmaxf(b1, red[w][4]); b2 = fmaxf(b2, red[w][5]);
            }
            float tx = trans[p * 3 + 0], ty = trans[p * 3 + 1], tz = trans[p * 3 + 2];
            float scale = 0.6f * fmaxf(b0 - a0, fmaxf(b1 - a1, b2 - a2));  // (1+0.2)*0.5
            c4s[0] = 0.5f * (a0 + b0) + tx;
            c4s[1] = 0.5f * (a1 + b1) + ty;
            c4s[2] = 0.5f * (a2 + b2) + tz;
            c4s[3] = scale;
        }
        __syncthreads();
    }
    float cx = c4s[0], cy = c4s[1], cz = c4s[2], s = c4s[3];
    float inv = 1.0f / s;
    float tx = trans[p * 3 + 0], ty = trans[p * 3 + 1], tz = trans[p * 3 + 2];
    float rg = (4.65f * inv) * 1.0005f + 0.005f;
    const float step = 2.0f / 31.0f;

    // --- 2. raster: wave-uniform 3x3x3, per-vert hoisted terms ------------
    #pragma unroll
    for (int gg = 0; gg < 2; ++gg) {
        int gi = tid + (gg << 10);
        if (gi < GH) {
            #pragma unroll
            for (int r4 = 0; r4 < 4; ++r4) {
                int r = (gg << 2) + r4;
                float wx = rx[r] + tx;
                float wy = ry[r] + ty;
                float wz = rz[r] + tz;
                float gvx = ((wx - cx) * inv + 1.0f) * 15.5f;
                float gvy = ((wy - cy) * inv + 1.0f) * 15.5f;
                float gvz = ((wz - cz) * inv + 1.0f) * 15.5f;
                int x0 = max(0, (int)ceilf(gvx - rg)), x1 = min(31, (int)floorf(gvx + rg));
                int y0 = max(0, (int)ceilf(gvy - rg)), y1 = min(31, (int)floorf(gvy + rg));
                int z0 = max(0, (int)ceilf(gvz - rg)), z1 = min(31, (int)floorf(gvz + rg));
                bool small = (x1 - x0 < 3) && (y1 - y0 < 3) && (z1 - z0 < 3);
                if (small) {
                    // hoisted per-vert terms (identical expressions -> same bits)
                    float dx2v[3], dyv[3], dzv[3];
                    #pragma unroll
                    for (int i = 0; i < 3; ++i) {
                        float qx = fmaf((float)(x0 + i), step, -1.0f) * s + cx;
                        float dx = qx - wx;
                        dx2v[i] = dx * dx;
                    }
                    #pragma unroll
                    for (int jj = 0; jj < 3; ++jj) {
                        float qy = fmaf((float)(y0 + jj), step, -1.0f) * s + cy;
                        dyv[jj] = qy - wy;
                    }
                    #pragma unroll
                    for (int k = 0; k < 3; ++k) {
                        float qz = fmaf((float)(z0 + k), step, -1.0f) * s + cz;
                        dzv[k] = qz - wz;
                    }
                    int b0 = (x0 << 10) | (y0 << 5) | z0;
                    #pragma unroll
                    for (int i = 0; i < 3; ++i) {
                        bool vx = (x0 + i <= x1);
                        #pragma unroll
                        for (int jj = 0; jj < 3; ++jj) {
                            float dxy = fmaf(dyv[jj], dyv[jj], dx2v[i]);
                            bool vxy = vx && (y0 + jj <= y1);
                            #pragma unroll
                            for (int k = 0; k < 3; ++k) {
                                float d2 = fmaf(dzv[k], dzv[k], dxy);
                                if (vxy && (z0 + k <= z1) && (d2 < 0.09f))
                                    atomicMin(&grid[b0 + (i << 10) + (jj << 5) + k],
                                              __float_as_int(d2));
                            }
                        }
                    }
                } else {
                    // fallback (span > 3): original divergent loop; never
                    // taken for this data, skipped wave-uniformly via execz.
                    for (int xi = x0; xi <= x1; ++xi) {
                        float qx = fmaf((float)xi, step, -1.0f) * s + cx;
                        float dx = qx - wx;
                        float dx2 = dx * dx;
                        if (dx2 >= 0.09f) continue;
                        for (int yi = y0; yi <= y1; ++yi) {
                            float qy = fmaf((float)yi, step, -1.0f) * s + cy;
                            float dy = qy - wy;
                            float dxy = fmaf(dy, dy, dx2);
                            if (dxy >= 0.09f) continue;
                            for (int zi = z0; zi <= z1; ++zi) {
                                float qz = fmaf((float)zi, step, -1.0f) * s + cz;
                                float dz = qz - wz;
                                float d2 = fmaf(dz, dz, dxy);
                                if (d2 < 0.09f)
                                    atomicMin(&grid[(xi << 10) | (yi << 5) | zi],
                                              __float_as_int(d2));
                            }
                        }
                    }
                }
            }
        }
    }
    // scalar tail raster (verts beyond held groups)
    for (int j = (GH << 2) + tid; j < V; j += 1024) {
        float wx = vp[3 * j + 0] + tx;
        float wy = vp[3 * j + 1] + ty;
        float wz = vp[3 * j + 2] + tz;
        float gvx = ((wx - cx) * inv + 1.0f) * 15.5f;
        float gvy = ((wy - cy) * inv + 1.0f) * 15.5f;
        float gvz = ((wz - cz) * inv + 1.0f) * 15.5f;
        int x0 = max(0, (int)ceilf(gvx - rg)), x1 = min(31, (int)floorf(gvx + rg));
        int y0 = max(0, (int)ceilf(gvy - rg)), y1 = min(31, (int)floorf(gvy + rg));
        int z0 = max(0, (int)ceilf(gvz - rg)), z1 = min(31, (int)floorf(gvz + rg));
        for (int xi = x0; xi <= x1; ++xi) {
            float qx = fmaf((float)xi, step, -1.0f) * s + cx;
            float dx = qx - wx;
            float dx2 = dx * dx;
            if (dx2 >= 0.09f) continue;
            for (int yi = y0; yi <= y1; ++yi) {
                float qy = fmaf((float)yi, step, -1.0f) * s + cy;
                float dy = qy - wy;
                float dxy = fmaf(dy, dy, dx2);
                if (dxy >= 0.09f) continue;
                for (int zi = z0; zi <= z1; ++zi) {
                    float qz = fmaf((float)zi, step, -1.0f) * s + cz;
                    float dz = qz - wz;
                    float d2 = fmaf(dz, dz, dxy);
                    if (d2 < 0.09f)
                        atomicMin(&grid[(xi << 10) | (yi << 5) | zi],
                                  __float_as_int(d2));
                }
            }
        }
    }
    __syncthreads();

    // --- 3. sample: index-stripe of each other person, gate-free ----------
    int P = *pP;
    int f = p / P, iloc = p - f * P;
    int jlo = (q * V) / Q, jhi = ((q + 1) * V) / Q;
    float acc = 0.0f;
    for (int jp = 0; jp < P; ++jp) {
        if (jp == iloc) continue;
        int pj = f * P + jp;
        const float* vj = verts + (size_t)pj * V * 3;
        float tjx = trans[pj * 3 + 0], tjy = trans[pj * 3 + 1], tjz = trans[pj * 3 + 2];
        for (int v = jlo + tid; v < jhi; v += 1024) {
            float wx = vj[3 * v + 0] + tjx;
            float wy = vj[3 * v + 1] + tjy;
            float wz = vj[3 * v + 2] + tjz;
            float gx = fminf(fmaxf(((wx - cx) / s + 1.0f) * 15.5f, 0.0f), 31.0f);
            float gy = fminf(fmaxf(((wy - cy) / s + 1.0f) * 15.5f, 0.0f), 31.0f);
            float gz = fminf(fmaxf(((wz - cz) / s + 1.0f) * 15.5f, 0.0f), 31.0f);
            int x0 = min((int)gx, 30);
            int y0 = min((int)gy, 30);
            int z0 = min((int)gz, 30);
            float fx = gx - (float)x0;
            float fy = gy - (float)y0;
            float fz = gz - (float)z0;
            int b = (x0 << 10) | (y0 << 5) | z0;
            float c000 = fmaxf(0.3f - sqrtf(__int_as_float(grid[b])), 0.0f);
            float c100 = fmaxf(0.3f - sqrtf(__int_as_float(grid[b + 1024])), 0.0f);
            float c010 = fmaxf(0.3f - sqrtf(__int_as_float(grid[b + 32])), 0.0f);
            float c110 = fmaxf(0.3f - sqrtf(__int_as_float(grid[b + 1056])), 0.0f);
            float c001 = fmaxf(0.3f - sqrtf(__int_as_float(grid[b + 1])), 0.0f);
            float c101 = fmaxf(0.3f - sqrtf(__int_as_float(grid[b + 1025])), 0.0f);
            float c011 = fmaxf(0.3f - sqrtf(__int_as_float(grid[b + 33])), 0.0f);
            float c111 = fmaxf(0.3f - sqrtf(__int_as_float(grid[b + 1057])), 0.0f);
            float c00 = c000 * (1.0f - fx) + c100 * fx;
            float c10 = c010 * (1.0f - fx) + c110 * fx;
            float c01 = c001 * (1.0f - fx) + c101 * fx;
            float c11 = c011 * (1.0f - fx) + c111 * fx;
            float c0 = c00 * (1.0f - fy) + c10 * fy;
            float c1 = c01 * (1.0f - fy) + c11 * fy;
            float sv = c0 * (1.0f - fz) + c1 * fz;
            acc += fmaxf(sv, 0.0f);
        }
    }
    for (int m = 32; m > 0; m >>= 1) acc += __shfl_xor(acc, m);
    if (lane == 0) racc[wave] = acc;
    __syncthreads();
    if (tid == 0) {
        float t = 0.0f;
        for (int w = 0; w < 16; ++w) t += racc[w];
        part[bq] = t;                       // unconditional -> no zero-init
    }
}

// ---------------------------------------------------------------------------
// Final: parallel weighted reduction (R12-proven, unchanged).
// ---------------------------------------------------------------------------
__global__ __launch_bounds__(256) void k_final(const float* __restrict__ part,
                                               const int* __restrict__ valid,
                                               const int* __restrict__ pP,
                                               float* __restrict__ out, int n) {
    __shared__ float snum[4], sden[4];
    int P = *pP;
    int F = n / P;
    int tot = n * Q;
    int tid = threadIdx.x, lane = tid & 63, wave = tid >> 6;
    float num = 0.0f;
    for (int i = tid; i < tot; i += 256) {
        int f = i / (P * Q);
        num += part[i] * (float)valid[f * P];
    }
    float den = 0.0f;
    for (int f = tid; f < F; f += 256) den += (float)valid[f * P];
    for (int m = 32; m > 0; m >>= 1) {
        num += __shfl_xor(num, m);
        den += __shfl_xor(den, m);
    }
    if (lane == 0) { snum[wave] = num; sden[wave] = den; }
    __syncthreads();
    if (tid == 0) {
        float tn = snum[0] + snum[1] + snum[2] + snum[3];
        float td = sden[0] + sden[1] + sden[2] + sden[3];
        out[0] = tn / td * (1000.0f / (float)(P * P));
    }
}

// ---------------------------------------------------------------------------
extern "C" void kernel_launch(void* const* d_in, const int* in_sizes, int n_in,
                              void* d_out, int out_size, void* d_ws, size_t ws_size,
                              hipStream_t stream) {
    const float* verts = (const float*)d_in[0];
    const float* trans = (const float*)d_in[1];
    const int*   valid = (const int*)d_in[2];       // int32 on device (harness)
    const int*   pP    = (const int*)d_in[5];       // num_people (device scalar)

    int n = in_sizes[1] / 3;                        // total persons
    int V = in_sizes[0] / in_sizes[1];              // vertices per person

    float* part = (float*)d_ws;                     // n*Q floats

    k_fused<<<n * Q, 1024, 0, stream>>>(verts, trans, part, V, n, pP);
    k_final<<<1, 256, 0, stream>>>(part, valid, pP, (float*)d_out, n);
}